// Round 5
// baseline (1734.268 us; speedup 1.0000x reference)
//
#include <hip/hip_runtime.h>
#include <stdint.h>

#pragma clang fp contract(off)

#define BATCH 16
#define CCH   512
#define NLEN  1024
#define NH    8
#define DH    64

// ================= numpy-pairwise emulation (f32, no contraction) =================
__device__ float pw128(const float* __restrict__ x) {
    float r0=x[0],r1=x[1],r2=x[2],r3=x[3],r4=x[4],r5=x[5],r6=x[6],r7=x[7];
    for (int i = 8; i < 128; i += 8) {
        r0 += x[i+0]; r1 += x[i+1]; r2 += x[i+2]; r3 += x[i+3];
        r4 += x[i+4]; r5 += x[i+5]; r6 += x[i+6]; r7 += x[i+7];
    }
    return ((r0+r1)+(r2+r3))+((r4+r5)+(r6+r7));
}
__device__ float pw128_sqdev(const float* __restrict__ x, float m) {
    float r0,r1,r2,r3,r4,r5,r6,r7;
    {
        float d;
        d = x[0]-m; r0 = d*d;  d = x[1]-m; r1 = d*d;
        d = x[2]-m; r2 = d*d;  d = x[3]-m; r3 = d*d;
        d = x[4]-m; r4 = d*d;  d = x[5]-m; r5 = d*d;
        d = x[6]-m; r6 = d*d;  d = x[7]-m; r7 = d*d;
    }
    for (int i = 8; i < 128; i += 8) {
        float d;
        d = x[i+0]-m; r0 += d*d;  d = x[i+1]-m; r1 += d*d;
        d = x[i+2]-m; r2 += d*d;  d = x[i+3]-m; r3 += d*d;
        d = x[i+4]-m; r4 += d*d;  d = x[i+5]-m; r5 += d*d;
        d = x[i+6]-m; r6 += d*d;  d = x[i+7]-m; r7 += d*d;
    }
    return ((r0+r1)+(r2+r3))+((r4+r5)+(r6+r7));
}

// BN stats, numpy semantics: mean = pairwise_sum/16384 (per-b 1024-runs pairwise,
// runs combined sequentially over b); var = mean((x-m)^2) two-pass; r = f32 1/sqrt(v+eps) CR.
__global__ __launch_bounds__(64) void bn_stats_np_k(const float* __restrict__ Y, int O,
                                                    float2* __restrict__ st)
{
    const int o = blockIdx.x;
    const int t = threadIdx.x;
    __shared__ float part[16];
    __shared__ float msh;
    if (t < 16) {
        const float* p = Y + ((size_t)t * O + o) * NLEN;
        float b0 = pw128(p), b1 = pw128(p+128), b2 = pw128(p+256), b3 = pw128(p+384);
        float b4 = pw128(p+512), b5 = pw128(p+640), b6 = pw128(p+768), b7 = pw128(p+896);
        part[t] = ((b0+b1)+(b2+b3))+((b4+b5)+(b6+b7));
    }
    __syncthreads();
    if (t == 0) {
        float s = part[0];
        for (int b = 1; b < 16; ++b) s += part[b];
        msh = s / 16384.0f;
    }
    __syncthreads();
    const float m = msh;
    if (t < 16) {
        const float* p = Y + ((size_t)t * O + o) * NLEN;
        float b0 = pw128_sqdev(p,     m), b1 = pw128_sqdev(p+128, m);
        float b2 = pw128_sqdev(p+256, m), b3 = pw128_sqdev(p+384, m);
        float b4 = pw128_sqdev(p+512, m), b5 = pw128_sqdev(p+640, m);
        float b6 = pw128_sqdev(p+768, m), b7 = pw128_sqdev(p+896, m);
        part[t] = ((b0+b1)+(b2+b3))+((b4+b5)+(b6+b7));
    }
    __syncthreads();
    if (t == 0) {
        float s = part[0];
        for (int b = 1; b < 16; ++b) s += part[b];
        float var = s / 16384.0f;
        float ve  = var + 1e-5f;
        float sq  = (float)sqrt((double)ve);    // correctly-rounded f32 sqrt
        float r   = (float)(1.0 / (double)sq);  // correctly-rounded f32 reciprocal
        st[o] = make_float2(m, r);
    }
}

// spike of bn output, f32 reference op order: ((y-m)*r)*g + b, then /2 - 1 >= 0
__device__ inline bool spike_f32(float y, float2 s, float g, float b) {
    float t1 = y - s.x;
    float t2 = t1 * s.y;
    float t3 = t2 * g;
    float t4 = t3 + b;
    float u  = t4 / 2.0f - 1.0f;
    return u >= 0.0f;
}

// ================= GEMM: Y[b,o,n] = sum_c W[o,c]*Xin[b,c,n], f32 sequential FMA over c =================
// MODE 0: Xin = Xf (f32)   MODE 1: Xin = u8 spikes   MODE 2: Xin = f32(Xf + Xs8)  (np: x1 = x + a in f32)
template<int MODE>
__global__ __launch_bounds__(256, 2) void gemm_k(
    const float* __restrict__ W, const float* __restrict__ Xf, const uint8_t* __restrict__ Xs8,
    const float* __restrict__ bias, float* __restrict__ Y,
    int O, int Cin, int N)
{
    __shared__ float Ws[16][132];
    __shared__ float Xs[16][128];
    const int b  = blockIdx.z;
    const size_t xbase = (size_t)b * Cin * N;
    float* Yb = Y + (size_t)b * O * N;
    const int o0 = blockIdx.y * 128;
    const int n0 = blockIdx.x * 128;
    const int t  = threadIdx.x;
    const int tx = t & 15, ty = t >> 4;

    float acc[8][8];
#pragma unroll
    for (int i = 0; i < 8; ++i)
#pragma unroll
        for (int j = 0; j < 8; ++j) acc[i][j] = 0.0f;

    const int wr = t >> 2;          // 0..63
    const int wk = (t & 3) << 2;    // 0,4,8,12
    const int xk = t >> 5;          // 0..7
    const int xc = (t & 31) << 2;   // 0..124

    for (int k0 = 0; k0 < Cin; k0 += 16) {
#pragma unroll
        for (int p = 0; p < 2; ++p) {
            int rr = wr + p * 64;
            float4 w4 = *reinterpret_cast<const float4*>(W + (size_t)(o0 + rr) * Cin + k0 + wk);
            Ws[wk + 0][rr] = w4.x; Ws[wk + 1][rr] = w4.y;
            Ws[wk + 2][rr] = w4.z; Ws[wk + 3][rr] = w4.w;
        }
#pragma unroll
        for (int p = 0; p < 2; ++p) {
            int kr = xk + p * 8;
            size_t off = xbase + (size_t)(k0 + kr) * N + n0 + xc;
            if (MODE == 0) {
                float4 v = *reinterpret_cast<const float4*>(Xf + off);
                Xs[kr][xc+0] = v.x; Xs[kr][xc+1] = v.y; Xs[kr][xc+2] = v.z; Xs[kr][xc+3] = v.w;
            } else if (MODE == 1) {
                uchar4 u = *reinterpret_cast<const uchar4*>(Xs8 + off);
                Xs[kr][xc+0] = (float)u.x; Xs[kr][xc+1] = (float)u.y;
                Xs[kr][xc+2] = (float)u.z; Xs[kr][xc+3] = (float)u.w;
            } else {
                float4 v = *reinterpret_cast<const float4*>(Xf + off);
                uchar4 u = *reinterpret_cast<const uchar4*>(Xs8 + off);
                Xs[kr][xc+0] = v.x + (float)u.x;   // f32 rounding = np's x1 = x + a
                Xs[kr][xc+1] = v.y + (float)u.y;
                Xs[kr][xc+2] = v.z + (float)u.z;
                Xs[kr][xc+3] = v.w + (float)u.w;
            }
        }
        __syncthreads();
#pragma unroll
        for (int kk = 0; kk < 16; ++kk) {
            float av[8], bv[8];
#pragma unroll
            for (int i = 0; i < 8; ++i) av[i] = Ws[kk][ty * 8 + i];
#pragma unroll
            for (int j = 0; j < 8; ++j) bv[j] = Xs[kk][tx * 8 + j];
#pragma unroll
            for (int i = 0; i < 8; ++i)
#pragma unroll
                for (int j = 0; j < 8; ++j)
                    acc[i][j] = fmaf(av[i], bv[j], acc[i][j]);   // strict sequential-c FMA chain
        }
        __syncthreads();
    }
#pragma unroll
    for (int i = 0; i < 8; ++i) {
        int o = o0 + ty * 8 + i;
        float bb = bias ? bias[o] : 0.0f;
#pragma unroll
        for (int j = 0; j < 8; ++j) {
            float r = acc[i][j] + bb;            // np: y = einsum(...) then + bias (separate f32 add)
            Yb[(size_t)o * N + n0 + tx * 8 + j] = r;
        }
    }
}

// ================= spike + transpose to [B,H,N,D] u8 =================
__global__ __launch_bounds__(256) void spike_pack_k(
    const float* __restrict__ Y, const float2* __restrict__ st,
    const float* __restrict__ g, const float* __restrict__ bet,
    uint8_t* __restrict__ out)
{
    const int nt = blockIdx.x, h = blockIdx.y, b = blockIdx.z;
    __shared__ uint8_t tile[64][68];
    const int t = threadIdx.x;
    {
        const int i = t & 63, dq = t >> 6;
#pragma unroll
        for (int p = 0; p < 16; ++p) {
            int d = dq * 16 + p;
            int c = h * 64 + d;
            float y = Y[((size_t)b * CCH + c) * NLEN + nt * 64 + i];
            tile[d][i] = spike_f32(y, st[c], g[c], bet[c]) ? 1 : 0;
        }
    }
    __syncthreads();
    {
        const int d = t & 63, iq = t >> 6;
#pragma unroll
        for (int p = 0; p < 16; ++p) {
            int i = iq * 16 + p;
            out[((size_t)(b * NH + h) * NLEN + nt * 64 + i) * DH + d] = tile[d][i];
        }
    }
}

// ================= M = K^T V  [B*H, 64, 64]  (exact integers) =================
__global__ __launch_bounds__(256) void ktv_k(const uint8_t* __restrict__ Kb, const uint8_t* __restrict__ Vb,
                                             float* __restrict__ M)
{
    const int bh = blockIdx.x;
    const uint8_t* kp = Kb + (size_t)bh * NLEN * DH;
    const uint8_t* vp = Vb + (size_t)bh * NLEN * DH;
    __shared__ float ks[64][68];
    __shared__ float vs[64][68];
    const int t = threadIdx.x;
    const int d2 = t & 63, g4 = t >> 6;
    float acc[16];
#pragma unroll
    for (int j = 0; j < 16; ++j) acc[j] = 0.f;

    for (int nc = 0; nc < NLEN; nc += 64) {
#pragma unroll
        for (int p = 0; p < 16; ++p) {
            int idx = t + p * 256;
            int r = idx >> 6, d = idx & 63;
            ks[r][d] = (float)kp[(size_t)(nc + r) * DH + d];
            vs[r][d] = (float)vp[(size_t)(nc + r) * DH + d];
        }
        __syncthreads();
        for (int n = 0; n < 64; ++n) {
            float vv = vs[n][d2];
#pragma unroll
            for (int j = 0; j < 16; ++j)
                acc[j] += ks[n][g4 * 16 + j] * vv;
        }
        __syncthreads();
    }
#pragma unroll
    for (int j = 0; j < 16; ++j)
        M[(size_t)bh * 4096 + (size_t)(g4 * 16 + j) * 64 + d2] = acc[j];
}

// ================= attn = Q @ M, integer spike attn>=8, write [B,C,N] u8 =================
__global__ __launch_bounds__(256) void attn_spike_k(const uint8_t* __restrict__ Qb, const float* __restrict__ M,
                                                    uint8_t* __restrict__ A)
{
    const int nt = blockIdx.x, h = blockIdx.y, b = blockIdx.z;
    const int bh = b * NH + h;
    __shared__ float Ms[64][68];
    __shared__ float qs[64][65];
    const int t = threadIdx.x;
#pragma unroll
    for (int p = 0; p < 16; ++p) {
        int idx = t + p * 256;
        int r = idx >> 6, c = idx & 63;
        Ms[r][c] = M[(size_t)bh * 4096 + idx];
        qs[c][r] = (float)Qb[((size_t)bh * NLEN + nt * 64 + r) * DH + c];
    }
    __syncthreads();
    const int n = t & 63, dg = t >> 6;
    float acc[16];
#pragma unroll
    for (int j = 0; j < 16; ++j) acc[j] = 0.f;
    for (int d1 = 0; d1 < 64; ++d1) {
        float qv = qs[d1][n];
#pragma unroll
        for (int j = 0; j < 16; ++j)
            acc[j] += qv * Ms[d1][dg * 16 + j];
    }
#pragma unroll
    for (int j = 0; j < 16; ++j) {
        int d = dg * 16 + j;
        // lif(attn*0.25): integer attn >= 8, exact in f32
        A[((size_t)b * CCH + h * 64 + d) * NLEN + nt * 64 + n] = (acc[j] >= 8.0f) ? 1 : 0;
    }
}

// ================= spike -> u8 store at channel offset =================
__global__ __launch_bounds__(256) void spike_store_k(
    const float* __restrict__ Y, const float2* __restrict__ st,
    const float* __restrict__ g, const float* __restrict__ bet,
    uint8_t* __restrict__ H, int Oc, int o_off, int Otot)
{
    size_t i4 = (size_t)blockIdx.x * 256 + threadIdx.x;
    size_t total = (size_t)BATCH * Oc * (NLEN / 4);
    if (i4 >= total) return;
    int n4 = (int)(i4 & 255);
    int o  = (int)((i4 >> 8) % Oc);
    int b  = (int)(i4 / ((size_t)256 * Oc));
    float4 y = reinterpret_cast<const float4*>(Y)[i4];
    float2 s = st[o];
    float gg = g[o], bb = bet[o];
    uchar4 r;
    r.x = spike_f32(y.x, s, gg, bb) ? 1 : 0;
    r.y = spike_f32(y.y, s, gg, bb) ? 1 : 0;
    r.z = spike_f32(y.z, s, gg, bb) ? 1 : 0;
    r.w = spike_f32(y.w, s, gg, bb) ? 1 : 0;
    *reinterpret_cast<uchar4*>(H + ((size_t)(b * Otot + o_off + o)) * NLEN + n4 * 4) = r;
}

// ================= out = (x + ares) + spike(bn(Y)) in np f32 order =================
__global__ __launch_bounds__(256) void final_k(
    const float* __restrict__ Y, const float2* __restrict__ st,
    const float* __restrict__ g, const float* __restrict__ bet,
    const float* __restrict__ x, const uint8_t* __restrict__ ares,
    float* __restrict__ Out)
{
    size_t i4 = (size_t)blockIdx.x * 256 + threadIdx.x;
    size_t total = (size_t)BATCH * CCH * (NLEN / 4);
    if (i4 >= total) return;
    int o = (int)((i4 >> 8) % CCH);
    float4 y  = reinterpret_cast<const float4*>(Y)[i4];
    float4 xv = reinterpret_cast<const float4*>(x)[i4];
    uchar4 av = reinterpret_cast<const uchar4*>(ares)[i4];
    float2 s = st[o];
    float gg = g[o], bb = bet[o];
    float4 r;
    {
        float x1;
        x1 = xv.x + (float)av.x; r.x = x1 + (spike_f32(y.x, s, gg, bb) ? 1.0f : 0.0f);
        x1 = xv.y + (float)av.y; r.y = x1 + (spike_f32(y.y, s, gg, bb) ? 1.0f : 0.0f);
        x1 = xv.z + (float)av.z; r.z = x1 + (spike_f32(y.z, s, gg, bb) ? 1.0f : 0.0f);
        x1 = xv.w + (float)av.w; r.w = x1 + (spike_f32(y.w, s, gg, bb) ? 1.0f : 0.0f);
    }
    reinterpret_cast<float4*>(Out)[i4] = r;
}

extern "C" void kernel_launch(void* const* d_in, const int* in_sizes, int n_in,
                              void* d_out, int out_size, void* d_ws, size_t ws_size,
                              hipStream_t stream)
{
    const float* x         = (const float*)d_in[0];
    const float* q_w       = (const float*)d_in[1];
    const float* q_g       = (const float*)d_in[2];
    const float* q_b       = (const float*)d_in[3];
    const float* k_w       = (const float*)d_in[4];
    const float* k_g       = (const float*)d_in[5];
    const float* k_b       = (const float*)d_in[6];
    const float* v_w       = (const float*)d_in[7];
    const float* v_g       = (const float*)d_in[8];
    const float* v_b       = (const float*)d_in[9];
    const float* proj_w    = (const float*)d_in[10];
    const float* proj_bias = (const float*)d_in[11];
    const float* proj_g    = (const float*)d_in[12];
    const float* proj_b    = (const float*)d_in[13];
    const float* fc1_w     = (const float*)d_in[14];
    const float* fc1_bias  = (const float*)d_in[15];
    const float* fc1_g     = (const float*)d_in[16];
    const float* fc1_b     = (const float*)d_in[17];
    const float* fc2_w     = (const float*)d_in[18];
    const float* fc2_bias  = (const float*)d_in[19];
    const float* fc2_g     = (const float*)d_in[20];
    const float* fc2_b     = (const float*)d_in[21];
    float* out = (float*)d_out;

    char* ws = (char*)d_ws;
    const size_t MiB = 1ull << 20;
    if (ws_size < 83 * MiB) return;

    // ---- layout (83 MiB) ----
    float*    Af    = (float*)(ws);                  // 32 MiB: f32 GEMM out (reused every stage)
    uint8_t*  ab    = (uint8_t*)(ws + 32 * MiB);     //  8 MiB: attention spikes [B,C,N]
    uint8_t*  ares  = (uint8_t*)(ws + 40 * MiB);     //  8 MiB: proj spikes, live to end
    uint8_t*  qb    = (uint8_t*)(ws + 48 * MiB);     //  8 MiB [B,H,N,D]
    uint8_t*  kb    = (uint8_t*)(ws + 56 * MiB);     //  8 MiB
    uint8_t*  vb    = (uint8_t*)(ws + 64 * MiB);     //  8 MiB
    uint8_t*  hb    = (uint8_t*)(ws + 48 * MiB);     // 32 MiB: fc1 spikes (overlays q/k/v after attn)
    float*    Mbuf  = (float*)(ws + 80 * MiB);       //  2 MiB
    float2*   stats = (float2*)(ws + 82 * MiB);      // 16 KiB

    dim3 thr(256);

    // --- q, k, v ---
    const float* Wt[3] = {q_w, k_w, v_w};
    const float* Gt[3] = {q_g, k_g, v_g};
    const float* Bt[3] = {q_b, k_b, v_b};
    uint8_t*     Pt[3] = {qb, kb, vb};
    for (int tsr = 0; tsr < 3; ++tsr) {
        gemm_k<0><<<dim3(8, 4, 16), thr, 0, stream>>>(Wt[tsr], x, nullptr, nullptr, Af, 512, 512, 1024);
        bn_stats_np_k<<<dim3(512), dim3(64), 0, stream>>>(Af, 512, stats);
        spike_pack_k<<<dim3(16, 8, 16), thr, 0, stream>>>(Af, stats, Gt[tsr], Bt[tsr], Pt[tsr]);
    }

    // --- attention (exact integers) ---
    ktv_k<<<dim3(128), thr, 0, stream>>>(kb, vb, Mbuf);
    attn_spike_k<<<dim3(16, 8, 16), thr, 0, stream>>>(qb, Mbuf, ab);

    // --- proj ---
    gemm_k<1><<<dim3(8, 4, 16), thr, 0, stream>>>(proj_w, nullptr, ab, proj_bias, Af, 512, 512, 1024);
    bn_stats_np_k<<<dim3(512), dim3(64), 0, stream>>>(Af, 512, stats);
    spike_store_k<<<dim3(8192), thr, 0, stream>>>(Af, stats, proj_g, proj_b, ares, 512, 0, 512);

    // --- fc1 on x1 = f32(x + ares), 4 chunks of 512 out-ch ---
    for (int ch = 0; ch < 4; ++ch) {
        gemm_k<2><<<dim3(8, 4, 16), thr, 0, stream>>>(fc1_w + (size_t)ch * 512 * 512, x, ares,
                                                      fc1_bias + ch * 512, Af, 512, 512, 1024);
        bn_stats_np_k<<<dim3(512), dim3(64), 0, stream>>>(Af, 512, stats);
        spike_store_k<<<dim3(8192), thr, 0, stream>>>(Af, stats, fc1_g + ch * 512, fc1_b + ch * 512,
                                                      hb, 512, ch * 512, 2048);
    }

    // --- fc2 + final residual ---
    gemm_k<1><<<dim3(8, 4, 16), thr, 0, stream>>>(fc2_w, nullptr, hb, fc2_bias, Af, 512, 2048, 1024);
    bn_stats_np_k<<<dim3(512), dim3(64), 0, stream>>>(Af, 512, stats);
    final_k<<<dim3(8192), thr, 0, stream>>>(Af, stats, fc2_g, fc2_b, x, ares, out);
}

// Round 6
// 1693.574 us; speedup vs baseline: 1.0240x; 1.0240x over previous
//
#include <hip/hip_runtime.h>
#include <stdint.h>

#pragma clang fp contract(off)

#define BATCH 16
#define CCH   512
#define NLEN  1024
#define NH    8
#define DH    64

// ================= numpy-pairwise emulation (f32, no contraction) =================
__device__ float pw128(const float* __restrict__ x) {
    float r0=x[0],r1=x[1],r2=x[2],r3=x[3],r4=x[4],r5=x[5],r6=x[6],r7=x[7];
    for (int i = 8; i < 128; i += 8) {
        r0 += x[i+0]; r1 += x[i+1]; r2 += x[i+2]; r3 += x[i+3];
        r4 += x[i+4]; r5 += x[i+5]; r6 += x[i+6]; r7 += x[i+7];
    }
    return ((r0+r1)+(r2+r3))+((r4+r5)+(r6+r7));
}
__device__ float pw128_sqdev(const float* __restrict__ x, float m) {
    float r0,r1,r2,r3,r4,r5,r6,r7;
    {
        float d;
        d = x[0]-m; r0 = d*d;  d = x[1]-m; r1 = d*d;
        d = x[2]-m; r2 = d*d;  d = x[3]-m; r3 = d*d;
        d = x[4]-m; r4 = d*d;  d = x[5]-m; r5 = d*d;
        d = x[6]-m; r6 = d*d;  d = x[7]-m; r7 = d*d;
    }
    for (int i = 8; i < 128; i += 8) {
        float d;
        d = x[i+0]-m; r0 += d*d;  d = x[i+1]-m; r1 += d*d;
        d = x[i+2]-m; r2 += d*d;  d = x[i+3]-m; r3 += d*d;
        d = x[i+4]-m; r4 += d*d;  d = x[i+5]-m; r5 += d*d;
        d = x[i+6]-m; r6 += d*d;  d = x[i+7]-m; r7 += d*d;
    }
    return ((r0+r1)+(r2+r3))+((r4+r5)+(r6+r7));
}

// BN stats, numpy semantics (bit-exact): pairwise mean, two-pass var, CR f32 rsqrt.
__global__ __launch_bounds__(64) void bn_stats_np_k(const float* __restrict__ Y, int O,
                                                    float2* __restrict__ st)
{
    const int o = blockIdx.x;
    const int t = threadIdx.x;
    __shared__ float part[16];
    __shared__ float msh;
    if (t < 16) {
        const float* p = Y + ((size_t)t * O + o) * NLEN;
        float b0 = pw128(p), b1 = pw128(p+128), b2 = pw128(p+256), b3 = pw128(p+384);
        float b4 = pw128(p+512), b5 = pw128(p+640), b6 = pw128(p+768), b7 = pw128(p+896);
        part[t] = ((b0+b1)+(b2+b3))+((b4+b5)+(b6+b7));
    }
    __syncthreads();
    if (t == 0) {
        float s = part[0];
        for (int b = 1; b < 16; ++b) s += part[b];
        msh = s / 16384.0f;
    }
    __syncthreads();
    const float m = msh;
    if (t < 16) {
        const float* p = Y + ((size_t)t * O + o) * NLEN;
        float b0 = pw128_sqdev(p,     m), b1 = pw128_sqdev(p+128, m);
        float b2 = pw128_sqdev(p+256, m), b3 = pw128_sqdev(p+384, m);
        float b4 = pw128_sqdev(p+512, m), b5 = pw128_sqdev(p+640, m);
        float b6 = pw128_sqdev(p+768, m), b7 = pw128_sqdev(p+896, m);
        part[t] = ((b0+b1)+(b2+b3))+((b4+b5)+(b6+b7));
    }
    __syncthreads();
    if (t == 0) {
        float s = part[0];
        for (int b = 1; b < 16; ++b) s += part[b];
        float var = s / 16384.0f;
        float ve  = var + 1e-5f;
        float sq  = (float)sqrt((double)ve);    // correctly-rounded f32 sqrt
        float r   = (float)(1.0 / (double)sq);  // correctly-rounded f32 reciprocal
        st[o] = make_float2(m, r);
    }
}

// spike of bn output, f32 reference op order
__device__ inline bool spike_f32(float y, float2 s, float g, float b) {
    float t1 = y - s.x;
    float t2 = t1 * s.y;
    float t3 = t2 * g;
    float t4 = t3 + b;
    float u  = t4 / 2.0f - 1.0f;
    return u >= 0.0f;
}

// ================= GEMM v2: 128x128 tile, 512 threads, BK=32, prefetch =================
// Bit-exactness invariant: each output element is one thread's strict sequential
// ascending-c f32 FMA chain (matches np einsum), bias added once at the end.
// MODE 0: X = Xf (f32)   MODE 1: X = u8 spikes   MODE 2: X = f32(Xf + Xs8)
template<int MODE>
__global__ __launch_bounds__(512, 2) void gemm_k(
    const float* __restrict__ W, const float* __restrict__ Xf, const uint8_t* __restrict__ Xs8,
    const float* __restrict__ bias, float* __restrict__ Y,
    int O, int Cin, int N)
{
    __shared__ float Ws[32][132];   // [k][o]
    __shared__ float Xs[32][132];   // [k][n], 132: 16B-aligned rows + bank spread
    const int b = blockIdx.z;
    const size_t xbase = (size_t)b * Cin * N;
    float* Yb = Y + (size_t)b * O * N;
    const int o0 = blockIdx.y * 128;
    const int n0 = blockIdx.x * 128;
    const int t  = threadIdx.x;
    const int tx = t & 15;          // n quad-group: cols tx*4 and 64+tx*4
    const int ty = t >> 4;          // 0..31: o rows ty*4 .. ty*4+3

    const int wr = t >> 2;          // 0..127  W row
    const int wk = (t & 3) << 3;    // 0,8,16,24
    const int xk = t >> 4;          // 0..31   X k-row
    const int xc = (t & 15) << 3;   // 0..120

    float acc[4][8];
#pragma unroll
    for (int i = 0; i < 4; ++i)
#pragma unroll
        for (int j = 0; j < 8; ++j) acc[i][j] = 0.0f;

    float4 wA0, wA1;
    float  xr[8];

    auto loadG = [&](int k0) {
        const float* wp = W + (size_t)(o0 + wr) * Cin + k0 + wk;
        wA0 = *reinterpret_cast<const float4*>(wp);
        wA1 = *reinterpret_cast<const float4*>(wp + 4);
        size_t off = xbase + (size_t)(k0 + xk) * N + n0 + xc;
        if (MODE == 0) {
            float4 v0 = *reinterpret_cast<const float4*>(Xf + off);
            float4 v1 = *reinterpret_cast<const float4*>(Xf + off + 4);
            xr[0]=v0.x; xr[1]=v0.y; xr[2]=v0.z; xr[3]=v0.w;
            xr[4]=v1.x; xr[5]=v1.y; xr[6]=v1.z; xr[7]=v1.w;
        } else if (MODE == 1) {
            uchar4 u0 = *reinterpret_cast<const uchar4*>(Xs8 + off);
            uchar4 u1 = *reinterpret_cast<const uchar4*>(Xs8 + off + 4);
            xr[0]=(float)u0.x; xr[1]=(float)u0.y; xr[2]=(float)u0.z; xr[3]=(float)u0.w;
            xr[4]=(float)u1.x; xr[5]=(float)u1.y; xr[6]=(float)u1.z; xr[7]=(float)u1.w;
        } else {
            float4 v0 = *reinterpret_cast<const float4*>(Xf + off);
            float4 v1 = *reinterpret_cast<const float4*>(Xf + off + 4);
            uchar4 u0 = *reinterpret_cast<const uchar4*>(Xs8 + off);
            uchar4 u1 = *reinterpret_cast<const uchar4*>(Xs8 + off + 4);
            xr[0]=v0.x+(float)u0.x; xr[1]=v0.y+(float)u0.y;
            xr[2]=v0.z+(float)u0.z; xr[3]=v0.w+(float)u0.w;
            xr[4]=v1.x+(float)u1.x; xr[5]=v1.y+(float)u1.y;
            xr[6]=v1.z+(float)u1.z; xr[7]=v1.w+(float)u1.w;
        }
    };
    auto stage = [&]() {
        Ws[wk+0][wr]=wA0.x; Ws[wk+1][wr]=wA0.y; Ws[wk+2][wr]=wA0.z; Ws[wk+3][wr]=wA0.w;
        Ws[wk+4][wr]=wA1.x; Ws[wk+5][wr]=wA1.y; Ws[wk+6][wr]=wA1.z; Ws[wk+7][wr]=wA1.w;
        *reinterpret_cast<float4*>(&Xs[xk][xc])     = make_float4(xr[0],xr[1],xr[2],xr[3]);
        *reinterpret_cast<float4*>(&Xs[xk][xc + 4]) = make_float4(xr[4],xr[5],xr[6],xr[7]);
    };

    loadG(0);
    stage();
    __syncthreads();
    for (int k0 = 0;;) {
        const int kn = k0 + 32;
        const bool more = kn < Cin;
        if (more) loadG(kn);
#pragma unroll
        for (int kk = 0; kk < 32; ++kk) {
            float4 a  = *reinterpret_cast<const float4*>(&Ws[kk][ty * 4]);
            float4 b0 = *reinterpret_cast<const float4*>(&Xs[kk][tx * 4]);
            float4 b1 = *reinterpret_cast<const float4*>(&Xs[kk][64 + tx * 4]);
            float av[4] = {a.x, a.y, a.z, a.w};
            float bv[8] = {b0.x, b0.y, b0.z, b0.w, b1.x, b1.y, b1.z, b1.w};
#pragma unroll
            for (int i = 0; i < 4; ++i)
#pragma unroll
                for (int j = 0; j < 8; ++j)
                    acc[i][j] = fmaf(av[i], bv[j], acc[i][j]);   // strict sequential-c chain
        }
        if (!more) break;
        __syncthreads();
        stage();
        __syncthreads();
        k0 = kn;
    }
#pragma unroll
    for (int i = 0; i < 4; ++i) {
        const int o = o0 + ty * 4 + i;
        const float bb = bias ? bias[o] : 0.0f;
        float* yp = Yb + (size_t)o * N + n0;
        float4 r0, r1;
        r0.x = acc[i][0] + bb; r0.y = acc[i][1] + bb;
        r0.z = acc[i][2] + bb; r0.w = acc[i][3] + bb;
        r1.x = acc[i][4] + bb; r1.y = acc[i][5] + bb;
        r1.z = acc[i][6] + bb; r1.w = acc[i][7] + bb;
        *reinterpret_cast<float4*>(yp + tx * 4)      = r0;
        *reinterpret_cast<float4*>(yp + 64 + tx * 4) = r1;
    }
}

// ================= spike + transpose to [B,H,N,D] u8 =================
__global__ __launch_bounds__(256) void spike_pack_k(
    const float* __restrict__ Y, const float2* __restrict__ st,
    const float* __restrict__ g, const float* __restrict__ bet,
    uint8_t* __restrict__ out)
{
    const int nt = blockIdx.x, h = blockIdx.y, b = blockIdx.z;
    __shared__ uint8_t tile[64][68];
    const int t = threadIdx.x;
    {
        const int i = t & 63, dq = t >> 6;
#pragma unroll
        for (int p = 0; p < 16; ++p) {
            int d = dq * 16 + p;
            int c = h * 64 + d;
            float y = Y[((size_t)b * CCH + c) * NLEN + nt * 64 + i];
            tile[d][i] = spike_f32(y, st[c], g[c], bet[c]) ? 1 : 0;
        }
    }
    __syncthreads();
    {
        const int d = t & 63, iq = t >> 6;
#pragma unroll
        for (int p = 0; p < 16; ++p) {
            int i = iq * 16 + p;
            out[((size_t)(b * NH + h) * NLEN + nt * 64 + i) * DH + d] = tile[d][i];
        }
    }
}

// ================= M = K^T V  [B*H, 64, 64]  (exact integers) =================
__global__ __launch_bounds__(256) void ktv_k(const uint8_t* __restrict__ Kb, const uint8_t* __restrict__ Vb,
                                             float* __restrict__ M)
{
    const int bh = blockIdx.x;
    const uint8_t* kp = Kb + (size_t)bh * NLEN * DH;
    const uint8_t* vp = Vb + (size_t)bh * NLEN * DH;
    __shared__ float ks[64][68];
    __shared__ float vs[64][68];
    const int t = threadIdx.x;
    const int d2 = t & 63, g4 = t >> 6;
    float acc[16];
#pragma unroll
    for (int j = 0; j < 16; ++j) acc[j] = 0.f;

    for (int nc = 0; nc < NLEN; nc += 64) {
#pragma unroll
        for (int p = 0; p < 16; ++p) {
            int idx = t + p * 256;
            int r = idx >> 6, d = idx & 63;
            ks[r][d] = (float)kp[(size_t)(nc + r) * DH + d];
            vs[r][d] = (float)vp[(size_t)(nc + r) * DH + d];
        }
        __syncthreads();
        for (int n = 0; n < 64; ++n) {
            float vv = vs[n][d2];
#pragma unroll
            for (int j = 0; j < 16; ++j)
                acc[j] += ks[n][g4 * 16 + j] * vv;
        }
        __syncthreads();
    }
#pragma unroll
    for (int j = 0; j < 16; ++j)
        M[(size_t)bh * 4096 + (size_t)(g4 * 16 + j) * 64 + d2] = acc[j];
}

// ================= attn = Q @ M, integer spike attn>=8, write [B,C,N] u8 =================
__global__ __launch_bounds__(256) void attn_spike_k(const uint8_t* __restrict__ Qb, const float* __restrict__ M,
                                                    uint8_t* __restrict__ A)
{
    const int nt = blockIdx.x, h = blockIdx.y, b = blockIdx.z;
    const int bh = b * NH + h;
    __shared__ float Ms[64][68];
    __shared__ float qs[64][65];
    const int t = threadIdx.x;
#pragma unroll
    for (int p = 0; p < 16; ++p) {
        int idx = t + p * 256;
        int r = idx >> 6, c = idx & 63;
        Ms[r][c] = M[(size_t)bh * 4096 + idx];
        qs[c][r] = (float)Qb[((size_t)bh * NLEN + nt * 64 + r) * DH + c];
    }
    __syncthreads();
    const int n = t & 63, dg = t >> 6;
    float acc[16];
#pragma unroll
    for (int j = 0; j < 16; ++j) acc[j] = 0.f;
    for (int d1 = 0; d1 < 64; ++d1) {
        float qv = qs[d1][n];
#pragma unroll
        for (int j = 0; j < 16; ++j)
            acc[j] += qv * Ms[d1][dg * 16 + j];
    }
#pragma unroll
    for (int j = 0; j < 16; ++j) {
        int d = dg * 16 + j;
        A[((size_t)b * CCH + h * 64 + d) * NLEN + nt * 64 + n] = (acc[j] >= 8.0f) ? 1 : 0;
    }
}

// ================= spike -> u8 store at channel offset =================
__global__ __launch_bounds__(256) void spike_store_k(
    const float* __restrict__ Y, const float2* __restrict__ st,
    const float* __restrict__ g, const float* __restrict__ bet,
    uint8_t* __restrict__ H, int Oc, int o_off, int Otot)
{
    size_t i4 = (size_t)blockIdx.x * 256 + threadIdx.x;
    size_t total = (size_t)BATCH * Oc * (NLEN / 4);
    if (i4 >= total) return;
    int n4 = (int)(i4 & 255);
    int o  = (int)((i4 >> 8) % Oc);
    int b  = (int)(i4 / ((size_t)256 * Oc));
    float4 y = reinterpret_cast<const float4*>(Y)[i4];
    float2 s = st[o];
    float gg = g[o], bb = bet[o];
    uchar4 r;
    r.x = spike_f32(y.x, s, gg, bb) ? 1 : 0;
    r.y = spike_f32(y.y, s, gg, bb) ? 1 : 0;
    r.z = spike_f32(y.z, s, gg, bb) ? 1 : 0;
    r.w = spike_f32(y.w, s, gg, bb) ? 1 : 0;
    *reinterpret_cast<uchar4*>(H + ((size_t)(b * Otot + o_off + o)) * NLEN + n4 * 4) = r;
}

// ================= out = (x + ares) + spike(bn(Y)) in np f32 order =================
__global__ __launch_bounds__(256) void final_k(
    const float* __restrict__ Y, const float2* __restrict__ st,
    const float* __restrict__ g, const float* __restrict__ bet,
    const float* __restrict__ x, const uint8_t* __restrict__ ares,
    float* __restrict__ Out)
{
    size_t i4 = (size_t)blockIdx.x * 256 + threadIdx.x;
    size_t total = (size_t)BATCH * CCH * (NLEN / 4);
    if (i4 >= total) return;
    int o = (int)((i4 >> 8) % CCH);
    float4 y  = reinterpret_cast<const float4*>(Y)[i4];
    float4 xv = reinterpret_cast<const float4*>(x)[i4];
    uchar4 av = reinterpret_cast<const uchar4*>(ares)[i4];
    float2 s = st[o];
    float gg = g[o], bb = bet[o];
    float4 r;
    {
        float x1;
        x1 = xv.x + (float)av.x; r.x = x1 + (spike_f32(y.x, s, gg, bb) ? 1.0f : 0.0f);
        x1 = xv.y + (float)av.y; r.y = x1 + (spike_f32(y.y, s, gg, bb) ? 1.0f : 0.0f);
        x1 = xv.z + (float)av.z; r.z = x1 + (spike_f32(y.z, s, gg, bb) ? 1.0f : 0.0f);
        x1 = xv.w + (float)av.w; r.w = x1 + (spike_f32(y.w, s, gg, bb) ? 1.0f : 0.0f);
    }
    reinterpret_cast<float4*>(Out)[i4] = r;
}

extern "C" void kernel_launch(void* const* d_in, const int* in_sizes, int n_in,
                              void* d_out, int out_size, void* d_ws, size_t ws_size,
                              hipStream_t stream)
{
    const float* x         = (const float*)d_in[0];
    const float* q_w       = (const float*)d_in[1];
    const float* q_g       = (const float*)d_in[2];
    const float* q_b       = (const float*)d_in[3];
    const float* k_w       = (const float*)d_in[4];
    const float* k_g       = (const float*)d_in[5];
    const float* k_b       = (const float*)d_in[6];
    const float* v_w       = (const float*)d_in[7];
    const float* v_g       = (const float*)d_in[8];
    const float* v_b       = (const float*)d_in[9];
    const float* proj_w    = (const float*)d_in[10];
    const float* proj_bias = (const float*)d_in[11];
    const float* proj_g    = (const float*)d_in[12];
    const float* proj_b    = (const float*)d_in[13];
    const float* fc1_w     = (const float*)d_in[14];
    const float* fc1_bias  = (const float*)d_in[15];
    const float* fc1_g     = (const float*)d_in[16];
    const float* fc1_b     = (const float*)d_in[17];
    const float* fc2_w     = (const float*)d_in[18];
    const float* fc2_bias  = (const float*)d_in[19];
    const float* fc2_g     = (const float*)d_in[20];
    const float* fc2_b     = (const float*)d_in[21];
    float* out = (float*)d_out;

    char* ws = (char*)d_ws;
    const size_t MiB = 1ull << 20;
    if (ws_size < 115 * MiB) return;

    // ---- layout (115 MiB) ----
    float*    Af    = (float*)(ws);                  // 64 MiB: f32 GEMM out (up to 1024 ch for fc1 chunks)
    uint8_t*  ab    = (uint8_t*)(ws + 64 * MiB);     //  8 MiB: attention spikes [B,C,N]
    uint8_t*  ares  = (uint8_t*)(ws + 72 * MiB);     //  8 MiB: proj spikes, live to end
    uint8_t*  qb    = (uint8_t*)(ws + 80 * MiB);     //  8 MiB [B,H,N,D]
    uint8_t*  kb    = (uint8_t*)(ws + 88 * MiB);     //  8 MiB
    uint8_t*  vb    = (uint8_t*)(ws + 96 * MiB);     //  8 MiB
    uint8_t*  hb    = (uint8_t*)(ws + 80 * MiB);     // 32 MiB: fc1 spikes (overlays q/k/v after attn)
    float*    Mbuf  = (float*)(ws + 112 * MiB);      //  2 MiB
    float2*   stats = (float2*)(ws + 114 * MiB);     // 16 KiB

    dim3 thr256(256), thr512(512);

    // --- q, k, v ---
    const float* Wt[3] = {q_w, k_w, v_w};
    const float* Gt[3] = {q_g, k_g, v_g};
    const float* Bt[3] = {q_b, k_b, v_b};
    uint8_t*     Pt[3] = {qb, kb, vb};
    for (int tsr = 0; tsr < 3; ++tsr) {
        gemm_k<0><<<dim3(8, 4, 16), thr512, 0, stream>>>(Wt[tsr], x, nullptr, nullptr, Af, 512, 512, 1024);
        bn_stats_np_k<<<dim3(512), dim3(64), 0, stream>>>(Af, 512, stats);
        spike_pack_k<<<dim3(16, 8, 16), thr256, 0, stream>>>(Af, stats, Gt[tsr], Bt[tsr], Pt[tsr]);
    }

    // --- attention (exact integers) ---
    ktv_k<<<dim3(128), thr256, 0, stream>>>(kb, vb, Mbuf);
    attn_spike_k<<<dim3(16, 8, 16), thr256, 0, stream>>>(qb, Mbuf, ab);

    // --- proj ---
    gemm_k<1><<<dim3(8, 4, 16), thr512, 0, stream>>>(proj_w, nullptr, ab, proj_bias, Af, 512, 512, 1024);
    bn_stats_np_k<<<dim3(512), dim3(64), 0, stream>>>(Af, 512, stats);
    spike_store_k<<<dim3(8192), thr256, 0, stream>>>(Af, stats, proj_g, proj_b, ares, 512, 0, 512);

    // --- fc1 on x1 = f32(x + ares), 2 chunks of 1024 out-ch ---
    for (int ch = 0; ch < 2; ++ch) {
        gemm_k<2><<<dim3(8, 8, 16), thr512, 0, stream>>>(fc1_w + (size_t)ch * 1024 * 512, x, ares,
                                                         fc1_bias + ch * 1024, Af, 1024, 512, 1024);
        bn_stats_np_k<<<dim3(1024), dim3(64), 0, stream>>>(Af, 1024, stats);
        spike_store_k<<<dim3(16384), thr256, 0, stream>>>(Af, stats, fc1_g + ch * 1024, fc1_b + ch * 1024,
                                                          hb, 1024, ch * 1024, 2048);
    }

    // --- fc2 + final residual ---
    gemm_k<1><<<dim3(8, 4, 16), thr512, 0, stream>>>(fc2_w, nullptr, hb, fc2_bias, Af, 512, 2048, 1024);
    bn_stats_np_k<<<dim3(512), dim3(64), 0, stream>>>(Af, 512, stats);
    final_k<<<dim3(8192), thr256, 0, stream>>>(Af, stats, fc2_g, fc2_b, x, ares, out);
}